// Round 9
// baseline (749.116 us; speedup 1.0000x reference)
//
#include <hip/hip_runtime.h>
#include <hip/hip_bf16.h>
#include <stdint.h>

typedef __attribute__((ext_vector_type(8))) short short8;
typedef __attribute__((ext_vector_type(8))) unsigned short ushort8;
typedef __attribute__((ext_vector_type(16))) float f32x16;
typedef __attribute__((ext_vector_type(8))) __bf16 bf16x8;

#define GAS __attribute__((address_space(1)))
#define LAS __attribute__((address_space(3)))

static constexpr int Bn = 16384;   // batch
static constexpr int Hn = 1024;    // hidden
static constexpr int KT = 4096;    // IN + H + CTX (concat K)
static constexpr int NT = KT / 64; // 64 K-tiles

#define SBAR()   __builtin_amdgcn_s_barrier()
#define VMCNT(n) asm volatile("s_waitcnt vmcnt(" #n ")" ::: "memory")
#define FENCE()  asm volatile("" ::: "memory")

__device__ __forceinline__ unsigned short f2bf(float f) {
  unsigned u = __builtin_bit_cast(unsigned, f);
  u = (u + 0x7FFFu + ((u >> 16) & 1u)) >> 16;   // RNE
  return (unsigned short)u;
}

__device__ __forceinline__ float fast_sigm(float x) {
  return __builtin_amdgcn_rcpf(1.f + __expf(-x));
}
__device__ __forceinline__ float fast_tanh(float x) {
  return 1.f - 2.f * __builtin_amdgcn_rcpf(__expf(2.f * x) + 1.f);
}

// Concat-convert 3 fp32 sources (widths 1024,1024,2048) into bf16 [rows][4096].
__global__ __launch_bounds__(256) void cvt_concat_k(
    const float* __restrict__ s0, const float* __restrict__ s1,
    const float* __restrict__ s2, unsigned short* __restrict__ dst,
    long long n8) {
  long long stride = (long long)gridDim.x * blockDim.x;
  for (long long g = (long long)blockIdx.x * blockDim.x + threadIdx.x; g < n8;
       g += stride) {
    long long row = g >> 9;
    int cg = (int)(g & 511) << 3;
    const float* src;
    if (cg < 1024)      src = s0 + row * 1024 + cg;
    else if (cg < 2048) src = s1 + row * 1024 + (cg - 1024);
    else                src = s2 + row * 2048 + (cg - 2048);
    float4 f0 = *(const float4*)src;
    float4 f1 = *(const float4*)(src + 4);
    ushort8 o;
    o[0] = f2bf(f0.x); o[1] = f2bf(f0.y); o[2] = f2bf(f0.z); o[3] = f2bf(f0.w);
    o[4] = f2bf(f1.x); o[5] = f2bf(f1.y); o[6] = f2bf(f1.z); o[7] = f2bf(f1.w);
    *(ushort8*)(dst + (g << 3)) = o;
  }
}

// Pack W|U|C into 32x32x16-MFMA B-frag records, WRITE-COALESCED.
// Record (k16g in 0..255, gf in 0..127) = 64 lanes x 16B at byte
//   (k16g*128 + gf)*1024 + lane*16   (lane-consecutive -> coalesced).
// Lane l of record: gemm-col = gate*1024 + h, gate = (gf&1)*2 + ((l>>4)&1),
//   h = (gf>>1)*16 + (l&15); k = k16g*16 + (l>>5)*8 + e (8 bf16).
__global__ __launch_bounds__(256) void cvt_pack_w(
    const float* __restrict__ s0, const float* __restrict__ s1,
    const float* __restrict__ s2, unsigned short* __restrict__ dst,
    long long ntot) {
  long long stride = (long long)gridDim.x * blockDim.x;
  for (long long g = (long long)blockIdx.x * blockDim.x + threadIdx.x; g < ntot;
       g += stride) {
    int l = (int)(g & 63);
    int gf = (int)((g >> 6) & 127);
    int k16g = (int)(g >> 13);
    int gate = ((gf & 1) << 1) | ((l >> 4) & 1);
    int row = (gate << 10) | ((gf >> 1) << 4) | (l & 15);
    int k0 = (k16g << 4) + ((l >> 5) << 3);
    const float* src;
    if (k0 < 1024)      src = s0 + (size_t)row * 1024 + k0;
    else if (k0 < 2048) src = s1 + (size_t)row * 1024 + (k0 - 1024);
    else                src = s2 + (size_t)row * 2048 + (k0 - 2048);
    float4 f0 = *(const float4*)src;
    float4 f1 = *(const float4*)(src + 4);
    ushort8 o;
    o[0] = f2bf(f0.x); o[1] = f2bf(f0.y); o[2] = f2bf(f0.z); o[3] = f2bf(f0.w);
    o[4] = f2bf(f1.x); o[5] = f2bf(f1.y); o[6] = f2bf(f1.z); o[7] = f2bf(f1.w);
    *(ushort8*)(dst + (g << 3)) = o;
  }
}

// 256x256 GEMM + fused LSTM on mfma_f32_32x32x16_bf16 (2495 TF pipe; half the
// MFMA instr count). 8 waves (2M x 4N), wave = 128 rows x 64 gemm-cols
// (4 m-frags x 2 s-frags x 4 k-steps = 32 MFMA/tile).
// A: LDS FRAG-MAJOR records (1KB = one wave operand, lane-consecutive ->
//    conflict-free by construction, no swizzle); 3 rotating 32KB buffers
//    staged 2 tiles ahead via global_load_lds (linear dest = HW semantics).
// B: frag-major packed global (cvt_pack_w), never in LDS; 8 coalesced 1KB
//    loads per wave per tile into parity register sets.
// Sync: ONE {VMCNT(12); s_barrier} per tile (identical ledger to r8: each
//    wave issues exactly 12 VMEM/tile = 8 B + 4 A; gate retires A staged 2
//    tiles ago; B regs compiler-waited). Never vmcnt(0) mid-loop.
// Gates: s-frag 0 = gates{0,1}, s-frag 1 = gates{2,3}; lanes l and l^16 hold
//    the gate pair for the SAME C/D rows -> epilogue uses 2 shfl_xor(16) per
//    reg; lo-lanes store c, hi-lanes store h.
__global__ __launch_bounds__(512, 2) void lstm_gemm(
    const unsigned short* __restrict__ X, const unsigned short* __restrict__ Wp,
    const float* __restrict__ bias, const float* __restrict__ c0,
    float* __restrict__ out_c, float* __restrict__ out_h) {
  extern __shared__ char smem[];  // 3 x 32KB A buffers (32 records each)

  int bid = blockIdx.x;
  int swz = (bid & 7) * 128 + (bid >> 3);  // 1024 blocks, 8 XCDs, bijective
  int mblk = swz >> 4, cblk = swz & 15;    // 16 consecutive share A-panel
  int brow0 = mblk * 256;
  int hcol0 = cblk * 64;

  int tid = threadIdx.x;
  int lane = tid & 63, wid = tid >> 6;
  int wr = wid >> 2, wc = wid & 3;  // 2M x 4N wave grid

  const char* Xc = (const char*)X;
  const char* Wpc = (const char*)Wp;

  // ---- A staging: record rec = wid*4+j -> (m32 = rec>>2, k16 = rec&3) ----
  uint32_t aoffj[4];
#pragma unroll
  for (int j = 0; j < 4; ++j) {
    int rec = wid * 4 + j;
    int m32 = rec >> 2, k16 = rec & 3;
    aoffj[j] = (uint32_t)(brow0 + m32 * 32 + (lane & 31)) * 8192u + k16 * 32 +
               ((lane >> 5) << 4);
  }

  auto stage_A = [&](int tt, int dbuf) {   // 32KB = 4 x 1KB-record gload_lds
    int ts = tt < NT ? tt : NT - 1;
#pragma unroll
    for (int j = 0; j < 4; ++j) {
      const char* src = Xc + aoffj[j] + (uint32_t)ts * 128u;
      char* dst = smem + dbuf * 32768 + (wid * 4 + j) * 1024;
      __builtin_amdgcn_global_load_lds((const GAS unsigned int*)src,
                                       (LAS unsigned int*)dst, 16, 0, 0);
    }
  };

  // ---- B frag-major per-lane base pointers (s = 0,1) ----
  const char* bbp[2];
#pragma unroll
  for (int s = 0; s < 2; ++s) {
    int gf = (cblk * 4 + wc) * 2 + s;
    bbp[s] = Wpc + (size_t)gf * 1024 + (lane << 4);
  }

  f32x16 acc[4][2] = {};     // [m][s]
  short8 bfrE[2][4], bfrO[2][4];  // [s][k16] parity sets

  // ---- prologue: A(0); B(0)->E; A(1)   (issue order pinned: 4,8,4) ----
  stage_A(0, 0);
  FENCE();
#pragma unroll
  for (int s = 0; s < 2; ++s)
#pragma unroll
    for (int k = 0; k < 4; ++k)
      bfrE[s][k] = *(const short8*)(bbp[s] + (size_t)k * 131072);
  FENCE();
  stage_A(1, 1);

  int bufA = 0;

#define TILE(T_, BC, BN)                                                      \
  {                                                                           \
    VMCNT(12);                                                                \
    SBAR();                                                                   \
    int pb = bufA * 32768;                                                    \
    int stg = bufA + 2; if (stg >= 3) stg -= 3;                               \
    _Pragma("unroll")                                                         \
    for (int q = 0; q < 4; ++q) {                                             \
      short8 a0 = *(const short8*)(smem + pb + (((wr * 4 + 0) * 4 + q) << 10) \
                                   + (lane << 4));                            \
      short8 a1 = *(const short8*)(smem + pb + (((wr * 4 + 1) * 4 + q) << 10) \
                                   + (lane << 4));                            \
      short8 a2 = *(const short8*)(smem + pb + (((wr * 4 + 2) * 4 + q) << 10) \
                                   + (lane << 4));                            \
      short8 a3 = *(const short8*)(smem + pb + (((wr * 4 + 3) * 4 + q) << 10) \
                                   + (lane << 4));                            \
      if (q == 1) {  /* coalesced B prefetch for T_+1, other parity */        \
        int ts = (T_) + 1 < NT ? (T_) + 1 : NT - 1;                           \
        size_t tb = (size_t)(4 * ts) * 131072u;                               \
        _Pragma("unroll")                                                     \
        for (int s = 0; s < 2; ++s)                                           \
          _Pragma("unroll")                                                   \
          for (int k = 0; k < 4; ++k)                                         \
            BN[s][k] = *(const short8*)(bbp[s] + tb + (size_t)k * 131072);    \
      }                                                                       \
      if (q == 3) stage_A((T_) + 2, stg);                                     \
      __builtin_amdgcn_s_setprio(1);                                          \
      _Pragma("unroll")                                                       \
      for (int s = 0; s < 2; ++s) {                                           \
        acc[0][s] = __builtin_amdgcn_mfma_f32_32x32x16_bf16(                  \
            __builtin_bit_cast(bf16x8, a0), __builtin_bit_cast(bf16x8, BC[s][q]),\
            acc[0][s], 0, 0, 0);                                              \
        acc[1][s] = __builtin_amdgcn_mfma_f32_32x32x16_bf16(                  \
            __builtin_bit_cast(bf16x8, a1), __builtin_bit_cast(bf16x8, BC[s][q]),\
            acc[1][s], 0, 0, 0);                                              \
        acc[2][s] = __builtin_amdgcn_mfma_f32_32x32x16_bf16(                  \
            __builtin_bit_cast(bf16x8, a2), __builtin_bit_cast(bf16x8, BC[s][q]),\
            acc[2][s], 0, 0, 0);                                              \
        acc[3][s] = __builtin_amdgcn_mfma_f32_32x32x16_bf16(                  \
            __builtin_bit_cast(bf16x8, a3), __builtin_bit_cast(bf16x8, BC[s][q]),\
            acc[3][s], 0, 0, 0);                                              \
      }                                                                       \
      __builtin_amdgcn_s_setprio(0);                                          \
    }                                                                         \
    bufA = bufA + 1; if (bufA >= 3) bufA = 0;                                 \
  }

  for (int t = 0; t < NT; t += 2) {
    TILE(t, bfrE, bfrO)
    TILE(t + 1, bfrO, bfrE)
  }
#undef TILE

  // ---- fused LSTM epilogue ----
  // C/D: col = lane&31 (in-frag), row = (reg&3)+8*(reg>>2)+4*(lane>>5).
  // s=0 holds gates{0,1}, s=1 gates{2,3}; partner lane = lane^16 (same rows).
  int col = hcol0 + wc * 16 + (lane & 15);
  float b0 = bias[col], b1 = bias[1024 + col];
  float b2 = bias[2048 + col], b3 = bias[3072 + col];
  bool hi = (lane & 16) != 0;
#pragma unroll
  for (int m = 0; m < 4; ++m) {
    int rbase = brow0 + (wr * 4 + m) * 32 + ((lane >> 5) << 2);
#pragma unroll
    for (int reg = 0; reg < 16; ++reg) {
      int grow = rbase + (reg & 3) + ((reg >> 2) << 3);
      size_t idx = (size_t)grow * 1024 + col;
      float v0 = acc[m][0][reg], v1 = acc[m][1][reg];
      float x0 = __shfl_xor(v0, 16);
      float x1 = __shfl_xor(v1, 16);
      float g0 = hi ? x0 : v0;
      float g1 = hi ? v0 : x0;
      float g2 = hi ? x1 : v1;
      float g3 = hi ? v1 : x1;
      float i_ = fast_sigm(g0 + b0);
      float f_ = fast_sigm(g1 + b1);
      float o_ = fast_sigm(g2 + b2);
      float ch = fast_tanh(g3 + b3);
      float cn = i_ * ch + f_ * c0[idx];
      if (!hi) out_c[idx] = cn;
      else     out_h[idx] = o_ * fast_tanh(cn);
    }
  }
}

// Fallback if ws too small (not expected; ws >= 160MB confirmed in round 1).
__global__ __launch_bounds__(256) void lstm_naive(
    const float* __restrict__ y, const float* __restrict__ ctx,
    const float* __restrict__ c0, const float* __restrict__ h0,
    const float* __restrict__ W, const float* __restrict__ U,
    const float* __restrict__ C, const float* __restrict__ b,
    float* __restrict__ out_c, float* __restrict__ out_h) {
  size_t t = (size_t)blockIdx.x * blockDim.x + threadIdx.x;
  if (t >= (size_t)Bn * Hn) return;
  int row = (int)(t >> 10), col = (int)(t & 1023);
  float g[4];
#pragma unroll
  for (int gg = 0; gg < 4; ++gg) {
    int wrow = gg * 1024 + col;
    float s = b[wrow];
    const float* yr = y + (size_t)row * 1024;
    const float* Wr = W + (size_t)wrow * 1024;
    for (int k = 0; k < 1024; ++k) s += yr[k] * Wr[k];
    const float* hr = h0 + (size_t)row * 1024;
    const float* Ur = U + (size_t)wrow * 1024;
    for (int k = 0; k < 1024; ++k) s += hr[k] * Ur[k];
    const float* cr = ctx + (size_t)row * 2048;
    const float* Cr = C + (size_t)wrow * 2048;
    for (int k = 0; k < 2048; ++k) s += cr[k] * Cr[k];
    g[gg] = s;
  }
  float i_ = fast_sigm(g[0]), f_ = fast_sigm(g[1]);
  float o_ = fast_sigm(g[2]), ch = fast_tanh(g[3]);
  float cn = i_ * ch + f_ * c0[t];
  out_c[t] = cn;
  out_h[t] = o_ * fast_tanh(cn);
}

extern "C" void kernel_launch(void* const* d_in, const int* in_sizes, int n_in,
                              void* d_out, int out_size, void* d_ws, size_t ws_size,
                              hipStream_t stream) {
  const float* y   = (const float*)d_in[0];
  const float* ctx = (const float*)d_in[1];
  const float* c0  = (const float*)d_in[2];
  const float* h0  = (const float*)d_in[3];
  const float* W   = (const float*)d_in[4];
  const float* U   = (const float*)d_in[5];
  const float* C   = (const float*)d_in[6];
  const float* b   = (const float*)d_in[7];
  float* out = (float*)d_out;
  float* out_c = out;
  float* out_h = out + (size_t)Bn * Hn;

  const size_t needX = (size_t)Bn * KT * 2;
  const size_t needW = (size_t)(4 * Hn) * KT * 2;

  if (ws_size >= needX + needW) {
    unsigned short* Xb = (unsigned short*)d_ws;
    unsigned short* Wb = (unsigned short*)((char*)d_ws + needX);
    cvt_concat_k<<<2048, 256, 0, stream>>>(y, h0, ctx, Xb, (long long)Bn * 512);
    cvt_pack_w<<<2048, 256, 0, stream>>>(W, U, C, Wb, (long long)(256 * 128 * 64));
    (void)hipFuncSetAttribute((const void*)lstm_gemm,
                              hipFuncAttributeMaxDynamicSharedMemorySize, 98304);
    lstm_gemm<<<1024, 512, 98304, stream>>>(Xb, Wb, b, c0, out_c, out_h);
  } else {
    lstm_naive<<<(Bn * Hn + 255) / 256, 256, 0, stream>>>(y, ctx, c0, h0, W, U, C,
                                                          b, out_c, out_h);
  }
}

// Round 10
// 556.668 us; speedup vs baseline: 1.3457x; 1.3457x over previous
//
#include <hip/hip_runtime.h>
#include <hip/hip_bf16.h>
#include <stdint.h>

typedef __attribute__((ext_vector_type(8))) short short8;
typedef __attribute__((ext_vector_type(8))) unsigned short ushort8;
typedef __attribute__((ext_vector_type(4))) float f32x4;
typedef __attribute__((ext_vector_type(8))) __bf16 bf16x8;

#define GAS __attribute__((address_space(1)))
#define LAS __attribute__((address_space(3)))

static constexpr int Bn = 16384;   // batch
static constexpr int Hn = 1024;    // hidden
static constexpr int KT = 4096;    // IN + H + CTX (concat K)
static constexpr int NT = KT / 64; // 64 K-tiles

#define SBAR()   __builtin_amdgcn_s_barrier()
#define VMCNT(n) asm volatile("s_waitcnt vmcnt(" #n ")" ::: "memory")
#define FENCE()  asm volatile("" ::: "memory")

__device__ __forceinline__ unsigned short f2bf(float f) {
  unsigned u = __builtin_bit_cast(unsigned, f);
  u = (u + 0x7FFFu + ((u >> 16) & 1u)) >> 16;   // RNE
  return (unsigned short)u;
}

__device__ __forceinline__ float fast_sigm(float x) {
  return __builtin_amdgcn_rcpf(1.f + __expf(-x));
}
__device__ __forceinline__ float fast_tanh(float x) {
  return 1.f - 2.f * __builtin_amdgcn_rcpf(__expf(2.f * x) + 1.f);
}

// Concat-convert 3 fp32 sources (widths 1024,1024,2048) into bf16 [rows][4096].
__global__ __launch_bounds__(256) void cvt_concat_k(
    const float* __restrict__ s0, const float* __restrict__ s1,
    const float* __restrict__ s2, unsigned short* __restrict__ dst,
    long long n8) {
  long long stride = (long long)gridDim.x * blockDim.x;
  for (long long g = (long long)blockIdx.x * blockDim.x + threadIdx.x; g < n8;
       g += stride) {
    long long row = g >> 9;
    int cg = (int)(g & 511) << 3;
    const float* src;
    if (cg < 1024)      src = s0 + row * 1024 + cg;
    else if (cg < 2048) src = s1 + row * 1024 + (cg - 1024);
    else                src = s2 + row * 2048 + (cg - 2048);
    float4 f0 = *(const float4*)src;
    float4 f1 = *(const float4*)(src + 4);
    ushort8 o;
    o[0] = f2bf(f0.x); o[1] = f2bf(f0.y); o[2] = f2bf(f0.z); o[3] = f2bf(f0.w);
    o[4] = f2bf(f1.x); o[5] = f2bf(f1.y); o[6] = f2bf(f1.z); o[7] = f2bf(f1.w);
    *(ushort8*)(dst + (g << 3)) = o;
  }
}

// Pack W|U|C into 16x16x32-MFMA B-frag records — WRITE-COALESCED.
// Record (k32 in 0..127, cb in 0..255) = 64 lanes x 16B at short-offset
//   (k32*256 + cb)*512 + li*8,  li = fr + ksl*16  (fr = col within 16-block,
//   ksl = k-slice). Thread g = ((k32*256+cb)<<6) + li -> consecutive threads
//   write consecutive 16B (fully coalesced). Reads gather 16 rows x 128B
//   contiguous segments per wave (every fetched byte used).
__global__ __launch_bounds__(256) void cvt_pack_w(
    const float* __restrict__ s0, const float* __restrict__ s1,
    const float* __restrict__ s2, unsigned short* __restrict__ dst,
    long long ntot) {
  long long stride = (long long)gridDim.x * blockDim.x;
  for (long long g = (long long)blockIdx.x * blockDim.x + threadIdx.x; g < ntot;
       g += stride) {
    int li = (int)(g & 63);
    long long rec = g >> 6;
    int cb = (int)(rec & 255);
    int k32 = (int)(rec >> 8);
    int fr = li & 15, ksl = li >> 4;
    int row = cb * 16 + fr;            // W-concat row = gemm column
    int k0 = k32 * 32 + ksl * 8;
    const float* src;
    if (k0 < 1024)      src = s0 + (size_t)row * 1024 + k0;
    else if (k0 < 2048) src = s1 + (size_t)row * 1024 + (k0 - 1024);
    else                src = s2 + (size_t)row * 2048 + (k0 - 2048);
    float4 f0 = *(const float4*)src;
    float4 f1 = *(const float4*)(src + 4);
    ushort8 o;
    o[0] = f2bf(f0.x); o[1] = f2bf(f0.y); o[2] = f2bf(f0.z); o[3] = f2bf(f0.w);
    o[4] = f2bf(f1.x); o[5] = f2bf(f1.y); o[6] = f2bf(f1.z); o[7] = f2bf(f1.w);
    *(ushort8*)(dst + (g << 3)) = o;
  }
}

// 256x256 GEMM + fused LSTM. 16x16x32 MFMA, 8 waves (2M x 4N).  [r8 verbatim]
// A: LDS via global_load_lds, 3 rotating 32KB buffers, staged 2 tiles ahead,
//    st_16x32 both-sides swizzle (conflict-free, verified r2-r8).
// B: NEVER in LDS — frag-major packed global (cvt_pack_w); each wave loads
//    8 coalesced 1KB frags per tile into parity register sets.
// Sync: ONE {VMCNT(12); s_barrier} per tile. Ledger: each wave issues exactly
//    12 VMEM/tile (8 B + 4 A); the gate retires A staged 2 tiles ago
//    (in-order retirement); B regs are compiler-waited. Never vmcnt(0)
//    mid-loop. Grid: A-panel-share + XCD-bijective swizzle.
__global__ __launch_bounds__(512, 2) void lstm_gemm(
    const unsigned short* __restrict__ X, const unsigned short* __restrict__ Wp,
    const float* __restrict__ bias, const float* __restrict__ c0,
    float* __restrict__ out_c, float* __restrict__ out_h) {
  extern __shared__ char smem[];  // 3 x 32KB A buffers

  int bid = blockIdx.x;
  int swz = (bid & 7) * 128 + (bid >> 3);  // 1024 blocks, 8 XCDs, bijective
  int mblk = swz >> 4, cblk = swz & 15;    // 16 consecutive share A-panel
  int brow0 = mblk * 256;
  int hcol0 = cblk * 64;

  int tid = threadIdx.x;
  int lane = tid & 63, wid = tid >> 6;
  int wr = wid >> 2, wc = wid & 3;  // 2M x 4N wave grid

  const char* Xc = (const char*)X;
  const char* Wpc = (const char*)Wp;

  // ---- A staging: inverse-swizzled global source, linear LDS dest ----
  int rr = tid >> 3;                                        // 0..63
  uint32_t cbyte = (uint32_t)(((tid & 7) * 16) ^ ((rr & 7) << 4));
  uint32_t aoffj[4];
#pragma unroll
  for (int j = 0; j < 4; ++j)
    aoffj[j] = (uint32_t)(brow0 + j * 64 + rr) * (KT * 2) + cbyte;

  auto stage_A = [&](int tt, int dbuf) {   // 32KB = 4 x global_load_lds
    int ts = tt < NT ? tt : NT - 1;
#pragma unroll
    for (int j = 0; j < 4; ++j) {
      const char* src = Xc + aoffj[j] + (uint32_t)ts * 128u;
      char* dst = smem + dbuf * 32768 + j * 8192 + wid * 1024;
      __builtin_amdgcn_global_load_lds((const GAS unsigned int*)src,
                                       (LAS unsigned int*)dst, 16, 0, 0);
    }
  };

  // ---- A ds_read swizzled offsets ----
  int kg = (lane >> 4) << 4;
  int sw = (lane & 7) << 4;
  int koff0 = kg ^ sw;
  int koff1 = (64 + kg) ^ sw;
  int fr = lane & 15;

  // ---- B frag-major per-lane base pointers (gate n) ----
  const char* bbp[4];
#pragma unroll
  for (int n = 0; n < 4; ++n) {
    int cb = n * 64 + cblk * 4 + wc;
    bbp[n] = Wpc + ((size_t)cb * 64 + lane) * 16;
  }

  f32x4 acc[8][4] = {};
  short8 bfrE[4][2], bfrO[4][2];   // B frag parity sets [n][k-slice]

  // ---- prologue: A(0); fence; B(0)->E + A(1)   (16 VMEM, A(0) oldest) ----
  stage_A(0, 0);
  FENCE();
#pragma unroll
  for (int n = 0; n < 4; ++n) {
    bfrE[n][0] = *(const short8*)(bbp[n]);
    bfrE[n][1] = *(const short8*)(bbp[n] + 262144);
  }
  stage_A(1, 1);

  int bufA = 0;

#define TILE(T_, BC, BN)                                                      \
  {                                                                           \
    VMCNT(12);                                                                \
    SBAR();                                                                   \
    int pb = bufA * 32768;                                                    \
    int stg = bufA + 2; if (stg >= 3) stg -= 3;                               \
    _Pragma("unroll")                                                         \
    for (int q = 0; q < 4; ++q) {                                             \
      int ab = pb + ((2 * q + wr) * 32 + fr) * 128;                           \
      short8 a0 = *(const short8*)(smem + ab + koff0);                        \
      short8 a1 = *(const short8*)(smem + ab + koff1);                        \
      short8 a2 = *(const short8*)(smem + ab + 2048 + koff0);                 \
      short8 a3 = *(const short8*)(smem + ab + 2048 + koff1);                 \
      if (q == 1) {  /* coalesced B prefetch for T_+1, other parity */        \
        int ts = (T_) + 1 < NT ? (T_) + 1 : NT - 1;                           \
        size_t tb = (size_t)(2 * ts) * 262144u;                               \
        _Pragma("unroll")                                                     \
        for (int n = 0; n < 4; ++n) {                                         \
          BN[n][0] = *(const short8*)(bbp[n] + tb);                           \
          BN[n][1] = *(const short8*)(bbp[n] + tb + 262144);                  \
        }                                                                     \
      }                                                                       \
      if (q == 3) stage_A((T_) + 2, stg);                                     \
      __builtin_amdgcn_s_setprio(1);                                          \
      _Pragma("unroll")                                                       \
      for (int n = 0; n < 4; ++n) {                                           \
        acc[2 * q][n] = __builtin_amdgcn_mfma_f32_16x16x32_bf16(              \
            __builtin_bit_cast(bf16x8, a0), __builtin_bit_cast(bf16x8, BC[n][0]),\
            acc[2 * q][n], 0, 0, 0);                                          \
        acc[2 * q + 1][n] = __builtin_amdgcn_mfma_f32_16x16x32_bf16(          \
            __builtin_bit_cast(bf16x8, a2), __builtin_bit_cast(bf16x8, BC[n][0]),\
            acc[2 * q + 1][n], 0, 0, 0);                                      \
      }                                                                       \
      _Pragma("unroll")                                                       \
      for (int n = 0; n < 4; ++n) {                                           \
        acc[2 * q][n] = __builtin_amdgcn_mfma_f32_16x16x32_bf16(              \
            __builtin_bit_cast(bf16x8, a1), __builtin_bit_cast(bf16x8, BC[n][1]),\
            acc[2 * q][n], 0, 0, 0);                                          \
        acc[2 * q + 1][n] = __builtin_amdgcn_mfma_f32_16x16x32_bf16(          \
            __builtin_bit_cast(bf16x8, a3), __builtin_bit_cast(bf16x8, BC[n][1]),\
            acc[2 * q + 1][n], 0, 0, 0);                                      \
      }                                                                       \
      __builtin_amdgcn_s_setprio(0);                                          \
    }                                                                         \
    bufA = bufA + 1; if (bufA >= 3) bufA = 0;                                 \
  }

  for (int t = 0; t < NT; t += 2) {
    TILE(t, bfrE, bfrO)
    TILE(t + 1, bfrO, bfrE)
  }
#undef TILE

  // ---- fused LSTM epilogue (acc[m][n]: n = gate) ----
  int col = hcol0 + wc * 16 + fr;
  float bi = bias[col], bf_ = bias[1024 + col];
  float bo = bias[2048 + col], bc = bias[3072 + col];
#pragma unroll
  for (int m = 0; m < 8; ++m) {
    int row0 = brow0 + (2 * (m >> 1) + wr) * 32 + (m & 1) * 16 + ((lane >> 4) << 2);
#pragma unroll
    for (int j = 0; j < 4; ++j) {
      size_t idx = (size_t)(row0 + j) * 1024 + col;
      float i_ = fast_sigm(acc[m][0][j] + bi);
      float f_ = fast_sigm(acc[m][1][j] + bf_);
      float o_ = fast_sigm(acc[m][2][j] + bo);
      float ch = fast_tanh(acc[m][3][j] + bc);
      float cn = i_ * ch + f_ * c0[idx];
      out_c[idx] = cn;
      out_h[idx] = o_ * fast_tanh(cn);
    }
  }
}

// Fallback if ws too small (not expected; ws >= 160MB confirmed in round 1).
__global__ __launch_bounds__(256) void lstm_naive(
    const float* __restrict__ y, const float* __restrict__ ctx,
    const float* __restrict__ c0, const float* __restrict__ h0,
    const float* __restrict__ W, const float* __restrict__ U,
    const float* __restrict__ C, const float* __restrict__ b,
    float* __restrict__ out_c, float* __restrict__ out_h) {
  size_t t = (size_t)blockIdx.x * blockDim.x + threadIdx.x;
  if (t >= (size_t)Bn * Hn) return;
  int row = (int)(t >> 10), col = (int)(t & 1023);
  float g[4];
#pragma unroll
  for (int gg = 0; gg < 4; ++gg) {
    int wrow = gg * 1024 + col;
    float s = b[wrow];
    const float* yr = y + (size_t)row * 1024;
    const float* Wr = W + (size_t)wrow * 1024;
    for (int k = 0; k < 1024; ++k) s += yr[k] * Wr[k];
    const float* hr = h0 + (size_t)row * 1024;
    const float* Ur = U + (size_t)wrow * 1024;
    for (int k = 0; k < 1024; ++k) s += hr[k] * Ur[k];
    const float* cr = ctx + (size_t)row * 2048;
    const float* Cr = C + (size_t)wrow * 2048;
    for (int k = 0; k < 2048; ++k) s += cr[k] * Cr[k];
    g[gg] = s;
  }
  float i_ = fast_sigm(g[0]), f_ = fast_sigm(g[1]);
  float o_ = fast_sigm(g[2]), ch = fast_tanh(g[3]);
  float cn = i_ * ch + f_ * c0[t];
  out_c[t] = cn;
  out_h[t] = o_ * fast_tanh(cn);
}

extern "C" void kernel_launch(void* const* d_in, const int* in_sizes, int n_in,
                              void* d_out, int out_size, void* d_ws, size_t ws_size,
                              hipStream_t stream) {
  const float* y   = (const float*)d_in[0];
  const float* ctx = (const float*)d_in[1];
  const float* c0  = (const float*)d_in[2];
  const float* h0  = (const float*)d_in[3];
  const float* W   = (const float*)d_in[4];
  const float* U   = (const float*)d_in[5];
  const float* C   = (const float*)d_in[6];
  const float* b   = (const float*)d_in[7];
  float* out = (float*)d_out;
  float* out_c = out;
  float* out_h = out + (size_t)Bn * Hn;

  const size_t needX = (size_t)Bn * KT * 2;
  const size_t needW = (size_t)(4 * Hn) * KT * 2;

  if (ws_size >= needX + needW) {
    unsigned short* Xb = (unsigned short*)d_ws;
    unsigned short* Wb = (unsigned short*)((char*)d_ws + needX);
    cvt_concat_k<<<2048, 256, 0, stream>>>(y, h0, ctx, Xb, (long long)Bn * 512);
    cvt_pack_w<<<2048, 256, 0, stream>>>(W, U, C, Wb,
                                         (long long)(4 * Hn) * KT / 8);
    (void)hipFuncSetAttribute((const void*)lstm_gemm,
                              hipFuncAttributeMaxDynamicSharedMemorySize, 98304);
    lstm_gemm<<<1024, 512, 98304, stream>>>(Xb, Wb, b, c0, out_c, out_h);
  } else {
    lstm_naive<<<(Bn * Hn + 255) / 256, 256, 0, stream>>>(y, ctx, c0, h0, W, U, C,
                                                          b, out_c, out_h);
  }
}